// Round 13
// baseline (123.705 us; speedup 1.0000x reference)
//
#include <hip/hip_runtime.h>
#include <stdint.h>

#define DEV __device__ __forceinline__

typedef __attribute__((ext_vector_type(4))) float f32x4;
typedef __attribute__((ext_vector_type(16))) float f32x16;
typedef __attribute__((ext_vector_type(8))) short s16x8;
typedef __attribute__((ext_vector_type(8))) __bf16 bf16x8;

constexpr int kB = 16, kC = 512, kN = 1024;
constexpr int kO = 1536;
constexpr int kG = 32, kCPG = 16;
constexpr float kEps = 1e-5f;
// 1/sqrt(128) * log2(e): folded into the Q store so attn softmax is raw exp2
constexpr float kQS = 0.08838834764831845f * 1.44269504088896f;

#if __has_builtin(__builtin_amdgcn_exp2f)
#define EXP2(x) __builtin_amdgcn_exp2f(x)
#else
#define EXP2(x) exp2f(x)
#endif

DEV unsigned short f2bf(float f) {
  union { float f; uint32_t u; } cv; cv.f = f;
  uint32_t u = cv.u;
  return (unsigned short)((u + 0x7FFFu + ((u >> 16) & 1u)) >> 16);
}

DEV unsigned short bfbits(float f) {
  __bf16 h = (__bf16)f;
  return __builtin_bit_cast(unsigned short, h);
}

DEV bf16x8 asbf(s16x8 v) { return __builtin_bit_cast(bf16x8, v); }

DEV uint32_t cvtpk(float a, float b) {
  uint32_t w;
  asm("v_cvt_pk_bf16_f32 %0, %1, %2" : "=v"(w) : "v"(a), "v"(b));
  return w;
}

DEV void gl_lds16(const void* g, void* l) {
  __builtin_amdgcn_global_load_lds(
      (const __attribute__((address_space(1))) uint32_t*)g,
      (__attribute__((address_space(3))) uint32_t*)l, 16, 0, 0);
}

// ---------------- weights fp32 -> bf16 (both convs in one launch) ----------------
__global__ __launch_bounds__(256) void k_wconv2(const float* __restrict__ qw,
                                                const float* __restrict__ pw,
                                                unsigned short* __restrict__ dq,
                                                unsigned short* __restrict__ dp) {
  const int nq = 1536 * 512 / 4, np = 512 * 512 / 4;
  int i = blockIdx.x * 256 + threadIdx.x;
  const float* src;
  unsigned short* dst;
  int j;
  if (i < nq) { src = qw; dst = dq; j = i; }
  else { j = i - nq; if (j >= np) return; src = pw; dst = dp; }
  f32x4 v = ((const f32x4*)src)[j];
  unsigned short o[4];
  o[0] = f2bf(v[0]); o[1] = f2bf(v[1]); o[2] = f2bf(v[2]); o[3] = f2bf(v[3]);
  ((uint2*)dst)[j] = *(uint2*)o;
}

// ---------------- fused GroupNorm: stats + apply + transpose-to-token-major ------------
// One block per (b,g); the 16ch x 1024tok group (64KB fp32) is staged in LDS once.
// bid = sub*128 + b*8 + group4 where g = group4*4 + sub: the 4 sub-blocks owning the
// four 32B chunks of each 128B xt line share bid%8 -> same XCD L2 -> writes merge.
__global__ __launch_bounds__(256, 2) void k_gn(const float* __restrict__ x,
                                               const float* __restrict__ gw,
                                               const float* __restrict__ gb,
                                               unsigned short* __restrict__ xt) {
  const int bid = blockIdx.x;
  const int sub = bid >> 7, rem = bid & 127;
  const int b = rem >> 3, group4 = rem & 7;
  const int g = group4 * 4 + sub;
  const int t = threadIdx.x;
  __shared__ float ld[16 * 1028];  // row pitch 1028 floats: 16B-aligned rows, 2-way banks
  __shared__ float rb[8], bc[2];
  const float* xb = x + ((size_t)b * kC + g * kCPG) * kN;
  float s = 0.f, s2 = 0.f;
#pragma unroll
  for (int p = 0; p < 16; ++p) {  // pass p stages channel row p (coalesced float4)
    f32x4 v = *(const f32x4*)(xb + p * kN + t * 4);
    s += v[0] + v[1] + v[2] + v[3];
    s2 += v[0] * v[0] + v[1] * v[1] + v[2] * v[2] + v[3] * v[3];
    *(f32x4*)(ld + p * 1028 + t * 4) = v;
  }
#pragma unroll
  for (int m = 32; m >= 1; m >>= 1) { s += __shfl_xor(s, m); s2 += __shfl_xor(s2, m); }
  const int lane = t & 63, wid = t >> 6;
  if (lane == 0) { rb[wid * 2] = s; rb[wid * 2 + 1] = s2; }
  __syncthreads();
  if (t == 0) {
    float S = rb[0] + rb[2] + rb[4] + rb[6];
    float S2 = rb[1] + rb[3] + rb[5] + rb[7];
    float mu = S * (1.f / 16384.f);
    float var = S2 * (1.f / 16384.f) - mu * mu;
    bc[0] = mu; bc[1] = rsqrtf(var + kEps);
  }
  __syncthreads();
  const float mu = bc[0], rs = bc[1];
  float a[16], bb[16];
#pragma unroll
  for (int ch = 0; ch < 16; ++ch) {
    a[ch] = rs * gw[g * kCPG + ch];
    bb[ch] = gb[g * kCPG + ch] - mu * a[ch];
  }
  // apply + write: thread t owns tokens 4t..4t+3; 2x16B stores per token
  const int n0 = t * 4;
  f32x4 col[16];
#pragma unroll
  for (int ch = 0; ch < 16; ++ch) col[ch] = *(const f32x4*)(ld + ch * 1028 + n0);
#pragma unroll
  for (int j = 0; j < 4; ++j) {
    unsigned short o[16];
#pragma unroll
    for (int ch = 0; ch < 16; ++ch) o[ch] = f2bf(col[ch][j] * a[ch] + bb[ch]);
    unsigned short* dst = xt + ((size_t)b * kN + n0 + j) * kC + g * kCPG;
    *(uint4*)(dst) = *(uint4*)(o);
    *(uint4*)(dst + 8) = *(uint4*)(o + 8);
  }
}

// ---------------- GEMM: D[n][o] = sum_c act[b][n][c] * W[o][c] ----------------
// T3+T4: BK=32, 3 LDS buffers, counted vmcnt(4) (never drains in main loop),
// raw s_barrier (no implicit vmcnt(0) drain), 1 barrier per K-step.
template <int MODE>
__global__ __launch_bounds__(256, 3) void k_gemm(const unsigned short* __restrict__ act,
                                                 const unsigned short* __restrict__ wb,
                                                 const float* __restrict__ bias,
                                                 unsigned short* __restrict__ qkT,
                                                 unsigned short* __restrict__ vbuf,
                                                 const float* __restrict__ xres,
                                                 float* __restrict__ outp) {
  int b = blockIdx.y;
  int nt = blockIdx.x & 7, ot = blockIdx.x >> 3;
  int n0 = nt << 7, o0 = ot << 7;
  int t = threadIdx.x, lane = t & 63, wid = t >> 6;
  int wr = wid >> 1, wc = wid & 1;
  __shared__ __align__(16) char smem[49152];  // 3x8KB A | 3x8KB B; epi tile reuses
  f32x4 acc[4][4];
  const f32x4 zf = {0.f, 0.f, 0.f, 0.f};
#pragma unroll
  for (int i = 0; i < 4; ++i)
#pragma unroll
    for (int j = 0; j < 4; ++j) acc[i][j] = zf;
  const size_t rowb = (size_t)b * kN;

  auto stage = [&](int buf, int kt2) {  // 4 vmcnt events per call
    const int k0 = kt2 << 5;
    char* dA = smem + buf * 8192;
    char* dB = smem + 24576 + buf * 8192;
#pragma unroll
    for (int p = 0; p < 2; ++p) {
      const int id = p * 256 + t;
      const int row = id >> 2, cp = id & 3;
      const int cl = cp ^ ((row >> 1) & 3);  // involution: dest pos p holds chunk p^s_r
      gl_lds16(act + (rowb + n0 + row) * (size_t)kC + k0 + cl * 8, dA + id * 16);
      gl_lds16(wb + (size_t)(o0 + row) * kC + k0 + cl * 8, dB + id * 16);
    }
  };

  stage(0, 0);
  stage(1, 1);
  int cur = 0, stg = 2;
#pragma unroll 1
  for (int kt = 0; kt < 16; ++kt) {
    if (kt < 15) {
      asm volatile("s_waitcnt vmcnt(4)" ::: "memory");  // cohort kt landed; kt+1 rides
    } else {
      asm volatile("s_waitcnt vmcnt(0)" ::: "memory");
    }
    __builtin_amdgcn_s_barrier();  // raw barrier: no implicit vmcnt drain
    if (kt < 14) stage(stg, kt + 2);
    const char* pA = smem + cur * 8192;
    const char* pB = smem + 24576 + cur * 8192;
    s16x8 af[4], bfr[4];
    const int c = lane >> 4;
#pragma unroll
    for (int i = 0; i < 4; ++i) {
      const int rA = wr * 64 + i * 16 + (lane & 15);
      af[i] = *(const s16x8*)(pA + rA * 64 + ((c ^ ((rA >> 1) & 3)) << 4));
      const int rB = wc * 64 + i * 16 + (lane & 15);
      bfr[i] = *(const s16x8*)(pB + rB * 64 + ((c ^ ((rB >> 1) & 3)) << 4));
    }
    __builtin_amdgcn_s_setprio(1);
#pragma unroll
    for (int i = 0; i < 4; ++i)
#pragma unroll
      for (int j = 0; j < 4; ++j)
        acc[i][j] = __builtin_amdgcn_mfma_f32_16x16x32_bf16(asbf(af[i]), asbf(bfr[j]),
                                                            acc[i][j], 0, 0, 0);
    __builtin_amdgcn_s_setprio(0);
    cur = (cur == 2) ? 0 : cur + 1;
    stg = (stg == 2) ? 0 : stg + 1;
  }

  if (MODE == 0) {
    if (o0 < 1024) {
      // Q/K: route through LDS for fully-coalesced 16B stores (256B/row)
      __syncthreads();  // all compute reads done; smem reusable
      const float sc = (o0 < 512) ? kQS : 1.0f;
      unsigned short* tile = (unsigned short*)smem;  // [128][136] u16 (34.8KB)
#pragma unroll
      for (int j = 0; j < 4; ++j) {
        const int o = wc * 64 + j * 16 + (lane & 15);
        const float bs = bias[o0 + o];
#pragma unroll
        for (int i = 0; i < 4; ++i)
#pragma unroll
          for (int r = 0; r < 4; ++r) {
            const int n = wr * 64 + i * 16 + ((lane >> 4) << 2) + r;
            tile[n * 136 + o] = f2bf((acc[i][j][r] + bs) * sc);
          }
      }
      __syncthreads();
#pragma unroll
      for (int it = 0; it < 8; ++it) {
        const int n = it * 16 + (t >> 4);
        const int c8 = t & 15;
        *(uint4*)(qkT + (rowb + n0 + n) * (size_t)kO + o0 + c8 * 8) =
            *(const uint4*)(tile + n * 136 + c8 * 8);
      }
    } else {
      // V: d-major packed, already 8B-vector stores
#pragma unroll
      for (int j = 0; j < 4; ++j) {
        const int o = o0 + wc * 64 + j * 16 + (lane & 15);
        const float bs = bias[o];
#pragma unroll
        for (int i = 0; i < 4; ++i) {
          const int nb = n0 + wr * 64 + ((lane >> 4) << 2) + i * 16;
          unsigned short pk[4];
#pragma unroll
          for (int r = 0; r < 4; ++r) pk[r] = f2bf(acc[i][j][r] + bs);
          *(uint2*)(vbuf + ((size_t)b * 512 + (o - 1024)) * kN + nb) = *(uint2*)pk;
        }
      }
    }
  } else {
    const int baseN = n0 + wr * 64 + ((lane >> 4) << 2);
#pragma unroll
    for (int j = 0; j < 4; ++j) {
      const int o = o0 + wc * 64 + j * 16 + (lane & 15);
      const float bs = bias[o];
#pragma unroll
      for (int i = 0; i < 4; ++i) {
        const int nb = baseN + i * 16;
        const size_t oo = ((size_t)b * kC + o) * kN + nb;
        const f32x4 xv = *(const f32x4*)(xres + oo);
        f32x4 ov;
        ov[0] = acc[i][j][0] + bs + xv[0];
        ov[1] = acc[i][j][1] + bs + xv[1];
        ov[2] = acc[i][j][2] + bs + xv[2];
        ov[3] = acc[i][j][3] + bs + xv[3];
        *(f32x4*)(outp + oo) = ov;
      }
    }
  }
}

// ---------------- flash attention v13: both QK halves up-front, deferred V-wait --------
// Per tile: [vmcnt(0); barrier] -> stageV(mt) -> stageK(mt+1)
//   -> QK^T half0 (sa0) -> QK^T half1 (sa1)   (32 back-to-back MFMAs)
//   -> exp2 + pack both halves (pure VALU; other wave's MFMAs overlap)
//   -> [vmcnt(4): V landed after riding ~whole tile; barrier] -> PV ks{0,1} -> PV ks{2,3}
// vs v9: V-latency exposure halved (rides across qk0+qk1+softmax, not just qk0);
// longer MFMA runs for cross-wave pipe interleave. +16 VGPR (both sa live) ~ 120 total.
__global__ __launch_bounds__(256, 3) void k_attn(const unsigned short* __restrict__ qkT,
                                                 const unsigned short* __restrict__ vbuf,
                                                 unsigned short* __restrict__ aoT) {
  const int bh = blockIdx.x, qt = blockIdx.y;
  const int b = bh >> 2, h = bh & 3;
  const int t = threadIdx.x, lane = t & 63, wid = t >> 6;
  const int l31 = lane & 31, hi = lane >> 5;
  __shared__ unsigned short sK[2][64 * 128];  // [m][d] swizzled, double-buffered (32KB)
  __shared__ unsigned short sV[128 * 64];     // [d][m] swizzled, single (16KB)
  __shared__ float sL[4][32];
  const int qrow0 = qt * 128 + wid * 32;
  // Q as B-operand frags: row n = qrow0+l31, k(d) = kk*16 + hi*8 + {0..7}
  s16x8 qf[8];
#pragma unroll
  for (int kk = 0; kk < 8; ++kk)
    qf[kk] = *(const s16x8*)(qkT + ((size_t)b * kN + qrow0 + l31) * kO + h * 128 +
                             kk * 16 + hi * 8);
  f32x16 oc[4];
#pragma unroll
  for (int df = 0; df < 4; ++df)
#pragma unroll
    for (int r = 0; r < 16; ++r) oc[df][r] = 0.f;
  float lpart = 0.f;

  auto stageK = [&](int buf, int m0) {  // 4 vmcnt events
#pragma unroll
    for (int p = 0; p < 4; ++p) {
      const int id = p * 256 + t;
      const int row = id >> 4, cp = id & 15, cl = cp ^ (row & 7);
      gl_lds16(qkT + ((size_t)b * kN + m0 + row) * kO + 512 + h * 128 + cl * 8,
               (char*)sK[buf] + (p * 256 + wid * 64) * 16);
    }
  };
  auto stageV = [&](int m0) {  // 4 vmcnt events
#pragma unroll
    for (int p = 0; p < 4; ++p) {
      const int id = p * 256 + t;
      const int row = id >> 3, cp = id & 7, cl = cp ^ (row & 7);
      gl_lds16(vbuf + ((size_t)b * 512 + h * 128 + row) * kN + m0 + cl * 8,
               (char*)sV + (p * 256 + wid * 64) * 16);
    }
  };
  // QK^T over 32 K-rows starting at rbase -> accumulator (no softmax here)
  auto qkhalf = [&](int cur, int rbase, f32x16& sa) {
#pragma unroll
    for (int r = 0; r < 16; ++r) sa[r] = 0.f;
    const int r0 = rbase + l31;
    __builtin_amdgcn_s_setprio(1);
#pragma unroll
    for (int kk = 0; kk < 8; ++kk) {
      const int c0 = kk * 2 + hi;
      s16x8 kf = *(const s16x8*)((const char*)sK[cur] + r0 * 256 + ((c0 ^ (r0 & 7)) << 4));
      sa = __builtin_amdgcn_mfma_f32_32x32x16_bf16(asbf(kf), asbf(qf[kk]), sa, 0, 0, 0);
    }
    __builtin_amdgcn_s_setprio(0);
  };
  // exp2 + pack one half's 16 scores into 2 ks-frags
  auto smpack = [&](const f32x16& sa, float& ps, uint32_t paw[2][4]) {
    float p[16];
#pragma unroll
    for (int r = 0; r < 16; ++r) { p[r] = EXP2(sa[r]); ps += p[r]; }
#pragma unroll
    for (int half = 0; half < 2; ++half) {
      const int base = half * 8;
      uint32_t a0 = cvtpk(p[base + 0], p[base + 1]);
      uint32_t b0 = cvtpk(p[base + 4], p[base + 5]);
      asm volatile("v_permlane32_swap_b32 %0, %1" : "+v"(a0), "+v"(b0));
      uint32_t a1 = cvtpk(p[base + 2], p[base + 3]);
      uint32_t b1 = cvtpk(p[base + 6], p[base + 7]);
      asm volatile("v_permlane32_swap_b32 %0, %1" : "+v"(a1), "+v"(b1));
      paw[half][0] = a0; paw[half][1] = a1; paw[half][2] = b0; paw[half][3] = b1;
    }
  };
  auto pv2 = [&](int ksbase, const uint32_t paw[2][4]) {  // PV for ks=ksbase,ksbase+1
    __builtin_amdgcn_s_setprio(1);
#pragma unroll
    for (int k2 = 0; k2 < 2; ++k2) {
      union { uint32_t w[4]; s16x8 v; } pa;
      pa.w[0] = paw[k2][0]; pa.w[1] = paw[k2][1]; pa.w[2] = paw[k2][2]; pa.w[3] = paw[k2][3];
      const int cv = (ksbase + k2) * 2 + hi;
#pragma unroll
      for (int df = 0; df < 4; ++df) {
        const int rv = df * 32 + l31;
        s16x8 vf = *(const s16x8*)((const char*)sV + rv * 128 + ((cv ^ (rv & 7)) << 4));
        oc[df] = __builtin_amdgcn_mfma_f32_32x32x16_bf16(asbf(pa.v), asbf(vf), oc[df], 0, 0, 0);
      }
    }
    __builtin_amdgcn_s_setprio(0);
  };

  stageK(0, 0);
#pragma unroll 1
  for (int mt = 0; mt < 16; ++mt) {
    const int cur = mt & 1;
    // top: K(mt) landed (only K outstanding); all waves done with sV + sK[cur^1]
    asm volatile("s_waitcnt vmcnt(0)" ::: "memory");
    __builtin_amdgcn_s_barrier();
    stageV(mt * 64);                              // V rides across qk0+qk1+softmax
    if (mt < 15) stageK(cur ^ 1, (mt + 1) * 64);  // K prefetch rides across whole tile
    // ---- both QK halves back-to-back (32 MFMAs), then softmax+pack both ----
    f32x16 sa0, sa1;
    qkhalf(cur, 0, sa0);
    qkhalf(cur, 32, sa1);
    float ps = 0.f;
    uint32_t paw0[2][4], paw1[2][4];
    smpack(sa0, ps, paw0);
    smpack(sa1, ps, paw1);
    lpart += ps;
    // mid: V(mt) landed (vmcnt(4): K(mt+1)'s 4 loads still fly); barrier => all waves'
    // V in AND all reads of sK[cur] complete. Last tile: no K prefetch -> drain 0.
    if (mt < 15) {
      asm volatile("s_waitcnt vmcnt(4)" ::: "memory");
    } else {
      asm volatile("s_waitcnt vmcnt(0)" ::: "memory");
    }
    __builtin_amdgcn_s_barrier();
    pv2(0, paw0);
    pv2(2, paw1);
  }
  // ---- finalize: row sums, normalize, store ----
  lpart += __shfl_xor(lpart, 32);  // combine hi/lo m-halves -> full row sum for n=l31
  if (hi == 0) sL[wid][l31] = lpart;
  float inv[16];
#pragma unroll
  for (int r = 0; r < 16; ++r) {
    const int crow = (r & 3) + 8 * (r >> 2) + 4 * hi;
    inv[r] = 1.f / sL[wid][crow];
  }
#pragma unroll
  for (int df = 0; df < 4; ++df) {
    const int d = df * 32 + l31;
#pragma unroll
    for (int r = 0; r < 16; ++r) {
      const int n = qrow0 + (r & 3) + 8 * (r >> 2) + 4 * hi;
      aoT[((size_t)b * kN + n) * kC + h * 128 + d] = bfbits(oc[df][r] * inv[r]);
    }
  }
}

extern "C" void kernel_launch(void* const* d_in, const int* in_sizes, int n_in,
                              void* d_out, int out_size, void* d_ws, size_t ws_size,
                              hipStream_t stream) {
  const float* x = (const float*)d_in[0];
  const float* norm_w = (const float*)d_in[1];
  const float* norm_b = (const float*)d_in[2];
  const float* qkv_w = (const float*)d_in[3];
  const float* qkv_b = (const float*)d_in[4];
  const float* proj_w = (const float*)d_in[5];
  const float* proj_b = (const float*)d_in[6];
  float* out = (float*)d_out;
  char* ws = (char*)d_ws;
  const size_t OFF_MEAN = 0;
  const size_t OFF_RSTD = 2048;
  const size_t OFF_WQ = 4096;
  const size_t OFF_WP = OFF_WQ + (size_t)1536 * 512 * 2;
  const size_t OFF_XT = OFF_WP + (size_t)512 * 512 * 2;
  const size_t OFF_QKT = OFF_XT + (size_t)16 * 1024 * 512 * 2;
  const size_t OFF_V = OFF_QKT + (size_t)16 * 1024 * 1536 * 2;
  const size_t NEED = OFF_V + (size_t)16 * 512 * 1024 * 2;  // ~86 MB
  if (ws_size < NEED) return;
  unsigned short* wq = (unsigned short*)(ws + OFF_WQ);
  unsigned short* wp = (unsigned short*)(ws + OFF_WP);
  unsigned short* xt = (unsigned short*)(ws + OFF_XT);
  unsigned short* qkT = (unsigned short*)(ws + OFF_QKT);
  unsigned short* vb = (unsigned short*)(ws + OFF_V);
  unsigned short* aoT = xt;  // xhat is dead after qkv GEMM; reuse for attn output

  k_wconv2<<<1024, 256, 0, stream>>>(qkv_w, proj_w, wq, wp);
  k_gn<<<512, 256, 0, stream>>>(x, norm_w, norm_b, xt);
  k_gemm<0><<<dim3(96, 16), 256, 0, stream>>>(xt, wq, qkv_b, qkT, vb, nullptr, nullptr);
  k_attn<<<dim3(64, 8), 256, 0, stream>>>(qkT, vb, aoT);
  k_gemm<1><<<dim3(32, 16), 256, 0, stream>>>(aoT, wp, proj_b, nullptr, nullptr, x, out);
}

// Round 14
// 117.609 us; speedup vs baseline: 1.0518x; 1.0518x over previous
//
#include <hip/hip_runtime.h>
#include <stdint.h>

#define DEV __device__ __forceinline__

typedef __attribute__((ext_vector_type(4))) float f32x4;
typedef __attribute__((ext_vector_type(16))) float f32x16;
typedef __attribute__((ext_vector_type(8))) short s16x8;
typedef __attribute__((ext_vector_type(8))) __bf16 bf16x8;

constexpr int kB = 16, kC = 512, kN = 1024;
constexpr int kO = 1536;
constexpr int kG = 32, kCPG = 16;
constexpr float kEps = 1e-5f;
// 1/sqrt(128) * log2(e): folded into the Q store so attn softmax is raw exp2
constexpr float kQS = 0.08838834764831845f * 1.44269504088896f;

#if __has_builtin(__builtin_amdgcn_exp2f)
#define EXP2(x) __builtin_amdgcn_exp2f(x)
#else
#define EXP2(x) exp2f(x)
#endif

DEV unsigned short f2bf(float f) {
  union { float f; uint32_t u; } cv; cv.f = f;
  uint32_t u = cv.u;
  return (unsigned short)((u + 0x7FFFu + ((u >> 16) & 1u)) >> 16);
}

DEV unsigned short bfbits(float f) {
  __bf16 h = (__bf16)f;
  return __builtin_bit_cast(unsigned short, h);
}

DEV bf16x8 asbf(s16x8 v) { return __builtin_bit_cast(bf16x8, v); }

DEV uint32_t cvtpk(float a, float b) {
  uint32_t w;
  asm("v_cvt_pk_bf16_f32 %0, %1, %2" : "=v"(w) : "v"(a), "v"(b));
  return w;
}

DEV void gl_lds16(const void* g, void* l) {
  __builtin_amdgcn_global_load_lds(
      (const __attribute__((address_space(1))) uint32_t*)g,
      (__attribute__((address_space(3))) uint32_t*)l, 16, 0, 0);
}

// ---------------- weights fp32 -> bf16 (both convs in one launch) ----------------
__global__ __launch_bounds__(256) void k_wconv2(const float* __restrict__ qw,
                                                const float* __restrict__ pw,
                                                unsigned short* __restrict__ dq,
                                                unsigned short* __restrict__ dp) {
  const int nq = 1536 * 512 / 4, np = 512 * 512 / 4;
  int i = blockIdx.x * 256 + threadIdx.x;
  const float* src;
  unsigned short* dst;
  int j;
  if (i < nq) { src = qw; dst = dq; j = i; }
  else { j = i - nq; if (j >= np) return; src = pw; dst = dp; }
  f32x4 v = ((const f32x4*)src)[j];
  unsigned short o[4];
  o[0] = f2bf(v[0]); o[1] = f2bf(v[1]); o[2] = f2bf(v[2]); o[3] = f2bf(v[3]);
  ((uint2*)dst)[j] = *(uint2*)o;
}

// ---------------- fused GroupNorm: stats + apply + transpose-to-token-major ------------
// One block per (b,g); the 16ch x 1024tok group (64KB fp32) is staged in LDS once.
// bid = sub*128 + b*8 + group4 where g = group4*4 + sub: the 4 sub-blocks owning the
// four 32B chunks of each 128B xt line share bid%8 -> same XCD L2 -> writes merge.
__global__ __launch_bounds__(256, 2) void k_gn(const float* __restrict__ x,
                                               const float* __restrict__ gw,
                                               const float* __restrict__ gb,
                                               unsigned short* __restrict__ xt) {
  const int bid = blockIdx.x;
  const int sub = bid >> 7, rem = bid & 127;
  const int b = rem >> 3, group4 = rem & 7;
  const int g = group4 * 4 + sub;
  const int t = threadIdx.x;
  __shared__ float ld[16 * 1028];  // row pitch 1028 floats: 16B-aligned rows, 2-way banks
  __shared__ float rb[8], bc[2];
  const float* xb = x + ((size_t)b * kC + g * kCPG) * kN;
  float s = 0.f, s2 = 0.f;
#pragma unroll
  for (int p = 0; p < 16; ++p) {  // pass p stages channel row p (coalesced float4)
    f32x4 v = *(const f32x4*)(xb + p * kN + t * 4);
    s += v[0] + v[1] + v[2] + v[3];
    s2 += v[0] * v[0] + v[1] * v[1] + v[2] * v[2] + v[3] * v[3];
    *(f32x4*)(ld + p * 1028 + t * 4) = v;
  }
#pragma unroll
  for (int m = 32; m >= 1; m >>= 1) { s += __shfl_xor(s, m); s2 += __shfl_xor(s2, m); }
  const int lane = t & 63, wid = t >> 6;
  if (lane == 0) { rb[wid * 2] = s; rb[wid * 2 + 1] = s2; }
  __syncthreads();
  if (t == 0) {
    float S = rb[0] + rb[2] + rb[4] + rb[6];
    float S2 = rb[1] + rb[3] + rb[5] + rb[7];
    float mu = S * (1.f / 16384.f);
    float var = S2 * (1.f / 16384.f) - mu * mu;
    bc[0] = mu; bc[1] = rsqrtf(var + kEps);
  }
  __syncthreads();
  const float mu = bc[0], rs = bc[1];
  float a[16], bb[16];
#pragma unroll
  for (int ch = 0; ch < 16; ++ch) {
    a[ch] = rs * gw[g * kCPG + ch];
    bb[ch] = gb[g * kCPG + ch] - mu * a[ch];
  }
  // apply + write: thread t owns tokens 4t..4t+3; 2x16B stores per token
  const int n0 = t * 4;
  f32x4 col[16];
#pragma unroll
  for (int ch = 0; ch < 16; ++ch) col[ch] = *(const f32x4*)(ld + ch * 1028 + n0);
#pragma unroll
  for (int j = 0; j < 4; ++j) {
    unsigned short o[16];
#pragma unroll
    for (int ch = 0; ch < 16; ++ch) o[ch] = f2bf(col[ch][j] * a[ch] + bb[ch]);
    unsigned short* dst = xt + ((size_t)b * kN + n0 + j) * kC + g * kCPG;
    *(uint4*)(dst) = *(uint4*)(o);
    *(uint4*)(dst + 8) = *(uint4*)(o + 8);
  }
}

// ---------------- GEMM: D[n][o] = sum_c act[b][n][c] * W[o][c] ----------------
// T3+T4: BK=32, 3 LDS buffers, counted vmcnt(4) (never drains in main loop),
// raw s_barrier (no implicit vmcnt(0) drain), 1 barrier per K-step.
template <int MODE>
__global__ __launch_bounds__(256, 3) void k_gemm(const unsigned short* __restrict__ act,
                                                 const unsigned short* __restrict__ wb,
                                                 const float* __restrict__ bias,
                                                 unsigned short* __restrict__ qkT,
                                                 unsigned short* __restrict__ vbuf,
                                                 const float* __restrict__ xres,
                                                 float* __restrict__ outp) {
  int b = blockIdx.y;
  int nt = blockIdx.x & 7, ot = blockIdx.x >> 3;
  int n0 = nt << 7, o0 = ot << 7;
  int t = threadIdx.x, lane = t & 63, wid = t >> 6;
  int wr = wid >> 1, wc = wid & 1;
  __shared__ __align__(16) char smem[49152];  // 3x8KB A | 3x8KB B; epi tile reuses
  f32x4 acc[4][4];
  const f32x4 zf = {0.f, 0.f, 0.f, 0.f};
#pragma unroll
  for (int i = 0; i < 4; ++i)
#pragma unroll
    for (int j = 0; j < 4; ++j) acc[i][j] = zf;
  const size_t rowb = (size_t)b * kN;

  auto stage = [&](int buf, int kt2) {  // 4 vmcnt events per call
    const int k0 = kt2 << 5;
    char* dA = smem + buf * 8192;
    char* dB = smem + 24576 + buf * 8192;
#pragma unroll
    for (int p = 0; p < 2; ++p) {
      const int id = p * 256 + t;
      const int row = id >> 2, cp = id & 3;
      const int cl = cp ^ ((row >> 1) & 3);  // involution: dest pos p holds chunk p^s_r
      gl_lds16(act + (rowb + n0 + row) * (size_t)kC + k0 + cl * 8, dA + id * 16);
      gl_lds16(wb + (size_t)(o0 + row) * kC + k0 + cl * 8, dB + id * 16);
    }
  };

  stage(0, 0);
  stage(1, 1);
  int cur = 0, stg = 2;
#pragma unroll 1
  for (int kt = 0; kt < 16; ++kt) {
    if (kt < 15) {
      asm volatile("s_waitcnt vmcnt(4)" ::: "memory");  // cohort kt landed; kt+1 rides
    } else {
      asm volatile("s_waitcnt vmcnt(0)" ::: "memory");
    }
    __builtin_amdgcn_s_barrier();  // raw barrier: no implicit vmcnt drain
    if (kt < 14) stage(stg, kt + 2);
    const char* pA = smem + cur * 8192;
    const char* pB = smem + 24576 + cur * 8192;
    s16x8 af[4], bfr[4];
    const int c = lane >> 4;
#pragma unroll
    for (int i = 0; i < 4; ++i) {
      const int rA = wr * 64 + i * 16 + (lane & 15);
      af[i] = *(const s16x8*)(pA + rA * 64 + ((c ^ ((rA >> 1) & 3)) << 4));
      const int rB = wc * 64 + i * 16 + (lane & 15);
      bfr[i] = *(const s16x8*)(pB + rB * 64 + ((c ^ ((rB >> 1) & 3)) << 4));
    }
    __builtin_amdgcn_s_setprio(1);
#pragma unroll
    for (int i = 0; i < 4; ++i)
#pragma unroll
      for (int j = 0; j < 4; ++j)
        acc[i][j] = __builtin_amdgcn_mfma_f32_16x16x32_bf16(asbf(af[i]), asbf(bfr[j]),
                                                            acc[i][j], 0, 0, 0);
    __builtin_amdgcn_s_setprio(0);
    cur = (cur == 2) ? 0 : cur + 1;
    stg = (stg == 2) ? 0 : stg + 1;
  }

  if (MODE == 0) {
    if (o0 < 1024) {
      // Q/K: route through LDS for fully-coalesced 16B stores (256B/row)
      __syncthreads();  // all compute reads done; smem reusable
      const float sc = (o0 < 512) ? kQS : 1.0f;
      unsigned short* tile = (unsigned short*)smem;  // [128][136] u16 (34.8KB)
#pragma unroll
      for (int j = 0; j < 4; ++j) {
        const int o = wc * 64 + j * 16 + (lane & 15);
        const float bs = bias[o0 + o];
#pragma unroll
        for (int i = 0; i < 4; ++i)
#pragma unroll
          for (int r = 0; r < 4; ++r) {
            const int n = wr * 64 + i * 16 + ((lane >> 4) << 2) + r;
            tile[n * 136 + o] = f2bf((acc[i][j][r] + bs) * sc);
          }
      }
      __syncthreads();
#pragma unroll
      for (int it = 0; it < 8; ++it) {
        const int n = it * 16 + (t >> 4);
        const int c8 = t & 15;
        *(uint4*)(qkT + (rowb + n0 + n) * (size_t)kO + o0 + c8 * 8) =
            *(const uint4*)(tile + n * 136 + c8 * 8);
      }
    } else {
      // V: d-major packed, already 8B-vector stores
#pragma unroll
      for (int j = 0; j < 4; ++j) {
        const int o = o0 + wc * 64 + j * 16 + (lane & 15);
        const float bs = bias[o];
#pragma unroll
        for (int i = 0; i < 4; ++i) {
          const int nb = n0 + wr * 64 + ((lane >> 4) << 2) + i * 16;
          unsigned short pk[4];
#pragma unroll
          for (int r = 0; r < 4; ++r) pk[r] = f2bf(acc[i][j][r] + bs);
          *(uint2*)(vbuf + ((size_t)b * 512 + (o - 1024)) * kN + nb) = *(uint2*)pk;
        }
      }
    }
  } else {
    const int baseN = n0 + wr * 64 + ((lane >> 4) << 2);
#pragma unroll
    for (int j = 0; j < 4; ++j) {
      const int o = o0 + wc * 64 + j * 16 + (lane & 15);
      const float bs = bias[o];
#pragma unroll
      for (int i = 0; i < 4; ++i) {
        const int nb = baseN + i * 16;
        const size_t oo = ((size_t)b * kC + o) * kN + nb;
        const f32x4 xv = *(const f32x4*)(xres + oo);
        f32x4 ov;
        ov[0] = acc[i][j][0] + bs + xv[0];
        ov[1] = acc[i][j][1] + bs + xv[1];
        ov[2] = acc[i][j][2] + bs + xv[2];
        ov[3] = acc[i][j][3] + bs + xv[3];
        *(f32x4*)(outp + oo) = ov;
      }
    }
  }
}

// ---------------- flash attention v9 (proven 52.0us): split-half S + single-buf V ------
// Per tile: [vmcnt(0); barrier] -> stageV -> stageK(next)
//   -> QK^T half0 (K rows 0-31, one f32x16) -> exp2 in place -> pack ks{0,1}
//   -> [vmcnt(4): V landed, K prefetch rides; barrier] -> PV ks{0,1}
//   -> QK^T half1 (K rows 32-63, SAME regs) -> exp2 -> pack ks{2,3} -> PV ks{2,3}
// The qk1/pv0 interleave across co-resident waves (phase diversity) is load-bearing:
// v13's "both QK halves first" variant regressed 52->59us by removing it.
__global__ __launch_bounds__(256, 3) void k_attn(const unsigned short* __restrict__ qkT,
                                                 const unsigned short* __restrict__ vbuf,
                                                 unsigned short* __restrict__ aoT) {
  const int bh = blockIdx.x, qt = blockIdx.y;
  const int b = bh >> 2, h = bh & 3;
  const int t = threadIdx.x, lane = t & 63, wid = t >> 6;
  const int l31 = lane & 31, hi = lane >> 5;
  __shared__ unsigned short sK[2][64 * 128];  // [m][d] swizzled, double-buffered (32KB)
  __shared__ unsigned short sV[128 * 64];     // [d][m] swizzled, single (16KB)
  __shared__ float sL[4][32];
  const int qrow0 = qt * 128 + wid * 32;
  // Q as B-operand frags: row n = qrow0+l31, k(d) = kk*16 + hi*8 + {0..7}
  s16x8 qf[8];
#pragma unroll
  for (int kk = 0; kk < 8; ++kk)
    qf[kk] = *(const s16x8*)(qkT + ((size_t)b * kN + qrow0 + l31) * kO + h * 128 +
                             kk * 16 + hi * 8);
  f32x16 oc[4];
#pragma unroll
  for (int df = 0; df < 4; ++df)
#pragma unroll
    for (int r = 0; r < 16; ++r) oc[df][r] = 0.f;
  float lpart = 0.f;

  auto stageK = [&](int buf, int m0) {  // 4 vmcnt events
#pragma unroll
    for (int p = 0; p < 4; ++p) {
      const int id = p * 256 + t;
      const int row = id >> 4, cp = id & 15, cl = cp ^ (row & 7);
      gl_lds16(qkT + ((size_t)b * kN + m0 + row) * kO + 512 + h * 128 + cl * 8,
               (char*)sK[buf] + (p * 256 + wid * 64) * 16);
    }
  };
  auto stageV = [&](int m0) {  // 4 vmcnt events
#pragma unroll
    for (int p = 0; p < 4; ++p) {
      const int id = p * 256 + t;
      const int row = id >> 3, cp = id & 7, cl = cp ^ (row & 7);
      gl_lds16(vbuf + ((size_t)b * 512 + h * 128 + row) * kN + m0 + cl * 8,
               (char*)sV + (p * 256 + wid * 64) * 16);
    }
  };
  // one S-half: QK^T over 32 K-rows -> exp2 -> pack 2 ks-frags; PV'd by caller
  auto qkhalf = [&](int cur, int rbase, float& ps, uint32_t paw[2][4]) {
    float p[16];
    {
      f32x16 sa;
#pragma unroll
      for (int r = 0; r < 16; ++r) sa[r] = 0.f;
      __builtin_amdgcn_s_setprio(1);
#pragma unroll
      for (int kk = 0; kk < 8; ++kk) {
        const int c0 = kk * 2 + hi;
        const int r0 = rbase + l31;
        s16x8 kf = *(const s16x8*)((const char*)sK[cur] + r0 * 256 + ((c0 ^ (r0 & 7)) << 4));
        sa = __builtin_amdgcn_mfma_f32_32x32x16_bf16(asbf(kf), asbf(qf[kk]), sa, 0, 0, 0);
      }
      __builtin_amdgcn_s_setprio(0);
#pragma unroll
      for (int r = 0; r < 16; ++r) { p[r] = EXP2(sa[r]); ps += p[r]; }
    }
#pragma unroll
    for (int half = 0; half < 2; ++half) {
      const int base = half * 8;
      uint32_t a0 = cvtpk(p[base + 0], p[base + 1]);
      uint32_t b0 = cvtpk(p[base + 4], p[base + 5]);
      asm volatile("v_permlane32_swap_b32 %0, %1" : "+v"(a0), "+v"(b0));
      uint32_t a1 = cvtpk(p[base + 2], p[base + 3]);
      uint32_t b1 = cvtpk(p[base + 6], p[base + 7]);
      asm volatile("v_permlane32_swap_b32 %0, %1" : "+v"(a1), "+v"(b1));
      paw[half][0] = a0; paw[half][1] = a1; paw[half][2] = b0; paw[half][3] = b1;
    }
  };
  auto pv2 = [&](int ksbase, const uint32_t paw[2][4]) {  // PV for ks=ksbase,ksbase+1
    __builtin_amdgcn_s_setprio(1);
#pragma unroll
    for (int k2 = 0; k2 < 2; ++k2) {
      union { uint32_t w[4]; s16x8 v; } pa;
      pa.w[0] = paw[k2][0]; pa.w[1] = paw[k2][1]; pa.w[2] = paw[k2][2]; pa.w[3] = paw[k2][3];
      const int cv = (ksbase + k2) * 2 + hi;
#pragma unroll
      for (int df = 0; df < 4; ++df) {
        const int rv = df * 32 + l31;
        s16x8 vf = *(const s16x8*)((const char*)sV + rv * 128 + ((cv ^ (rv & 7)) << 4));
        oc[df] = __builtin_amdgcn_mfma_f32_32x32x16_bf16(asbf(pa.v), asbf(vf), oc[df], 0, 0, 0);
      }
    }
    __builtin_amdgcn_s_setprio(0);
  };

  stageK(0, 0);
#pragma unroll 1
  for (int mt = 0; mt < 16; ++mt) {
    const int cur = mt & 1;
    // top: K(mt) landed (only K outstanding); all waves done with sV + sK[cur^1]
    asm volatile("s_waitcnt vmcnt(0)" ::: "memory");
    __builtin_amdgcn_s_barrier();
    stageV(mt * 64);                              // V first: drained by vmcnt(4) mid-tile
    if (mt < 15) stageK(cur ^ 1, (mt + 1) * 64);  // K prefetch rides across whole tile
    float ps = 0.f;
    uint32_t paw[2][4];
    // ---- half 0: K rows 0-31 -> S^T, softmax, pack ks{0,1} ----
    qkhalf(cur, 0, ps, paw);
    // mid: V(mt) landed (vmcnt(4): K(mt+1)'s 4 loads still fly); barrier => all waves' V in
    if (mt < 15) {
      asm volatile("s_waitcnt vmcnt(4)" ::: "memory");
    } else {
      asm volatile("s_waitcnt vmcnt(0)" ::: "memory");
    }
    __builtin_amdgcn_s_barrier();
    pv2(0, paw);
    // ---- half 1: K rows 32-63, same registers -> pack ks{2,3}, PV ----
    qkhalf(cur, 32, ps, paw);
    pv2(2, paw);
    lpart += ps;
  }
  // ---- finalize: row sums, normalize, store ----
  lpart += __shfl_xor(lpart, 32);  // combine hi/lo m-halves -> full row sum for n=l31
  if (hi == 0) sL[wid][l31] = lpart;
  float inv[16];
#pragma unroll
  for (int r = 0; r < 16; ++r) {
    const int crow = (r & 3) + 8 * (r >> 2) + 4 * hi;
    inv[r] = 1.f / sL[wid][crow];
  }
#pragma unroll
  for (int df = 0; df < 4; ++df) {
    const int d = df * 32 + l31;
#pragma unroll
    for (int r = 0; r < 16; ++r) {
      const int n = qrow0 + (r & 3) + 8 * (r >> 2) + 4 * hi;
      aoT[((size_t)b * kN + n) * kC + h * 128 + d] = bfbits(oc[df][r] * inv[r]);
    }
  }
}

extern "C" void kernel_launch(void* const* d_in, const int* in_sizes, int n_in,
                              void* d_out, int out_size, void* d_ws, size_t ws_size,
                              hipStream_t stream) {
  const float* x = (const float*)d_in[0];
  const float* norm_w = (const float*)d_in[1];
  const float* norm_b = (const float*)d_in[2];
  const float* qkv_w = (const float*)d_in[3];
  const float* qkv_b = (const float*)d_in[4];
  const float* proj_w = (const float*)d_in[5];
  const float* proj_b = (const float*)d_in[6];
  float* out = (float*)d_out;
  char* ws = (char*)d_ws;
  const size_t OFF_MEAN = 0;
  const size_t OFF_RSTD = 2048;
  const size_t OFF_WQ = 4096;
  const size_t OFF_WP = OFF_WQ + (size_t)1536 * 512 * 2;
  const size_t OFF_XT = OFF_WP + (size_t)512 * 512 * 2;
  const size_t OFF_QKT = OFF_XT + (size_t)16 * 1024 * 512 * 2;
  const size_t OFF_V = OFF_QKT + (size_t)16 * 1024 * 1536 * 2;
  const size_t NEED = OFF_V + (size_t)16 * 512 * 1024 * 2;  // ~86 MB
  if (ws_size < NEED) return;
  unsigned short* wq = (unsigned short*)(ws + OFF_WQ);
  unsigned short* wp = (unsigned short*)(ws + OFF_WP);
  unsigned short* xt = (unsigned short*)(ws + OFF_XT);
  unsigned short* qkT = (unsigned short*)(ws + OFF_QKT);
  unsigned short* vb = (unsigned short*)(ws + OFF_V);
  unsigned short* aoT = xt;  // xhat is dead after qkv GEMM; reuse for attn output

  k_wconv2<<<1024, 256, 0, stream>>>(qkv_w, proj_w, wq, wp);
  k_gn<<<512, 256, 0, stream>>>(x, norm_w, norm_b, xt);
  k_gemm<0><<<dim3(96, 16), 256, 0, stream>>>(xt, wq, qkv_b, qkT, vb, nullptr, nullptr);
  k_attn<<<dim3(64, 8), 256, 0, stream>>>(qkT, vb, aoT);
  k_gemm<1><<<dim3(32, 16), 256, 0, stream>>>(aoT, wp, proj_b, nullptr, nullptr, x, out);
}

// Round 15
// 113.596 us; speedup vs baseline: 1.0890x; 1.0353x over previous
//
#include <hip/hip_runtime.h>
#include <stdint.h>

#define DEV __device__ __forceinline__

typedef __attribute__((ext_vector_type(4))) float f32x4;
typedef __attribute__((ext_vector_type(16))) float f32x16;
typedef __attribute__((ext_vector_type(8))) short s16x8;
typedef __attribute__((ext_vector_type(8))) __bf16 bf16x8;

constexpr int kB = 16, kC = 512, kN = 1024;
constexpr int kO = 1536;
constexpr int kG = 32, kCPG = 16;
constexpr float kEps = 1e-5f;
// 1/sqrt(128) * log2(e): folded into the Q store so attn softmax is raw exp2
constexpr float kQS = 0.08838834764831845f * 1.44269504088896f;

#if __has_builtin(__builtin_amdgcn_exp2f)
#define EXP2(x) __builtin_amdgcn_exp2f(x)
#else
#define EXP2(x) exp2f(x)
#endif

DEV unsigned short f2bf(float f) {
  union { float f; uint32_t u; } cv; cv.f = f;
  uint32_t u = cv.u;
  return (unsigned short)((u + 0x7FFFu + ((u >> 16) & 1u)) >> 16);
}

DEV unsigned short bfbits(float f) {
  __bf16 h = (__bf16)f;
  return __builtin_bit_cast(unsigned short, h);
}

DEV bf16x8 asbf(s16x8 v) { return __builtin_bit_cast(bf16x8, v); }

DEV uint32_t cvtpk(float a, float b) {
  uint32_t w;
  asm("v_cvt_pk_bf16_f32 %0, %1, %2" : "=v"(w) : "v"(a), "v"(b));
  return w;
}

DEV void gl_lds16(const void* g, void* l) {
  __builtin_amdgcn_global_load_lds(
      (const __attribute__((address_space(1))) uint32_t*)g,
      (__attribute__((address_space(3))) uint32_t*)l, 16, 0, 0);
}

// ------- fused GroupNorm (blocks 0-511) + weight fp32->bf16 conversion (512-1535) ------
// gn: one block per (b,g); the 16ch x 1024tok group (64KB fp32) staged in LDS once.
// bid = sub*128 + b*8 + group4, g = group4*4 + sub: the 4 sub-blocks owning the four
// 32B chunks of each 128B xt line share bid%8 -> same XCD L2 -> writes merge.
// wconv blocks (no LDS use) backfill CUs during gn's drain -> their cost hides.
__global__ __launch_bounds__(256, 2) void k_gnw(const float* __restrict__ x,
                                                const float* __restrict__ gw,
                                                const float* __restrict__ gb,
                                                unsigned short* __restrict__ xt,
                                                const float* __restrict__ qw,
                                                const float* __restrict__ pw,
                                                unsigned short* __restrict__ dq,
                                                unsigned short* __restrict__ dp) {
  const int bid = blockIdx.x;
  const int t = threadIdx.x;
  if (bid >= 512) {
    // ---- weight conversion: 1024 blocks cover (1536*512 + 512*512)/4 f32x4 items ----
    const int nq = 1536 * 512 / 4, np = 512 * 512 / 4;
    int i = (bid - 512) * 256 + t;
    const float* src;
    unsigned short* dst;
    int j;
    if (i < nq) { src = qw; dst = dq; j = i; }
    else { j = i - nq; if (j >= np) return; src = pw; dst = dp; }
    f32x4 v = ((const f32x4*)src)[j];
    unsigned short o[4];
    o[0] = f2bf(v[0]); o[1] = f2bf(v[1]); o[2] = f2bf(v[2]); o[3] = f2bf(v[3]);
    ((uint2*)dst)[j] = *(uint2*)o;
    return;
  }
  // ---- GroupNorm body (identical to proven k_gn) ----
  const int sub = bid >> 7, rem = bid & 127;
  const int b = rem >> 3, group4 = rem & 7;
  const int g = group4 * 4 + sub;
  __shared__ float ld[16 * 1028];  // row pitch 1028 floats: 16B-aligned rows, 2-way banks
  __shared__ float rb[8], bc[2];
  const float* xb = x + ((size_t)b * kC + g * kCPG) * kN;
  float s = 0.f, s2 = 0.f;
#pragma unroll
  for (int p = 0; p < 16; ++p) {  // pass p stages channel row p (coalesced float4)
    f32x4 v = *(const f32x4*)(xb + p * kN + t * 4);
    s += v[0] + v[1] + v[2] + v[3];
    s2 += v[0] * v[0] + v[1] * v[1] + v[2] * v[2] + v[3] * v[3];
    *(f32x4*)(ld + p * 1028 + t * 4) = v;
  }
#pragma unroll
  for (int m = 32; m >= 1; m >>= 1) { s += __shfl_xor(s, m); s2 += __shfl_xor(s2, m); }
  const int lane = t & 63, wid = t >> 6;
  if (lane == 0) { rb[wid * 2] = s; rb[wid * 2 + 1] = s2; }
  __syncthreads();
  if (t == 0) {
    float S = rb[0] + rb[2] + rb[4] + rb[6];
    float S2 = rb[1] + rb[3] + rb[5] + rb[7];
    float mu = S * (1.f / 16384.f);
    float var = S2 * (1.f / 16384.f) - mu * mu;
    bc[0] = mu; bc[1] = rsqrtf(var + kEps);
  }
  __syncthreads();
  const float mu = bc[0], rs = bc[1];
  float a[16], bb[16];
#pragma unroll
  for (int ch = 0; ch < 16; ++ch) {
    a[ch] = rs * gw[g * kCPG + ch];
    bb[ch] = gb[g * kCPG + ch] - mu * a[ch];
  }
  // apply + write: thread t owns tokens 4t..4t+3; 2x16B stores per token
  const int n0 = t * 4;
  f32x4 col[16];
#pragma unroll
  for (int ch = 0; ch < 16; ++ch) col[ch] = *(const f32x4*)(ld + ch * 1028 + n0);
#pragma unroll
  for (int j = 0; j < 4; ++j) {
    unsigned short o[16];
#pragma unroll
    for (int ch = 0; ch < 16; ++ch) o[ch] = f2bf(col[ch][j] * a[ch] + bb[ch]);
    unsigned short* dst = xt + ((size_t)b * kN + n0 + j) * kC + g * kCPG;
    *(uint4*)(dst) = *(uint4*)(o);
    *(uint4*)(dst + 8) = *(uint4*)(o + 8);
  }
}

// ---------------- GEMM: D[n][o] = sum_c act[b][n][c] * W[o][c] ----------------
// T3+T4: BK=32, 3 LDS buffers, counted vmcnt(4) (never drains in main loop),
// raw s_barrier (no implicit vmcnt(0) drain), 1 barrier per K-step.
template <int MODE>
__global__ __launch_bounds__(256, 3) void k_gemm(const unsigned short* __restrict__ act,
                                                 const unsigned short* __restrict__ wb,
                                                 const float* __restrict__ bias,
                                                 unsigned short* __restrict__ qkT,
                                                 unsigned short* __restrict__ vbuf,
                                                 const float* __restrict__ xres,
                                                 float* __restrict__ outp) {
  int b = blockIdx.y;
  int nt = blockIdx.x & 7, ot = blockIdx.x >> 3;
  int n0 = nt << 7, o0 = ot << 7;
  int t = threadIdx.x, lane = t & 63, wid = t >> 6;
  int wr = wid >> 1, wc = wid & 1;
  __shared__ __align__(16) char smem[49152];  // 3x8KB A | 3x8KB B; epi tile reuses
  f32x4 acc[4][4];
  const f32x4 zf = {0.f, 0.f, 0.f, 0.f};
#pragma unroll
  for (int i = 0; i < 4; ++i)
#pragma unroll
    for (int j = 0; j < 4; ++j) acc[i][j] = zf;
  const size_t rowb = (size_t)b * kN;

  auto stage = [&](int buf, int kt2) {  // 4 vmcnt events per call
    const int k0 = kt2 << 5;
    char* dA = smem + buf * 8192;
    char* dB = smem + 24576 + buf * 8192;
#pragma unroll
    for (int p = 0; p < 2; ++p) {
      const int id = p * 256 + t;
      const int row = id >> 2, cp = id & 3;
      const int cl = cp ^ ((row >> 1) & 3);  // involution: dest pos p holds chunk p^s_r
      gl_lds16(act + (rowb + n0 + row) * (size_t)kC + k0 + cl * 8, dA + id * 16);
      gl_lds16(wb + (size_t)(o0 + row) * kC + k0 + cl * 8, dB + id * 16);
    }
  };

  stage(0, 0);
  stage(1, 1);
  int cur = 0, stg = 2;
#pragma unroll 1
  for (int kt = 0; kt < 16; ++kt) {
    if (kt < 15) {
      asm volatile("s_waitcnt vmcnt(4)" ::: "memory");  // cohort kt landed; kt+1 rides
    } else {
      asm volatile("s_waitcnt vmcnt(0)" ::: "memory");
    }
    __builtin_amdgcn_s_barrier();  // raw barrier: no implicit vmcnt drain
    if (kt < 14) stage(stg, kt + 2);
    const char* pA = smem + cur * 8192;
    const char* pB = smem + 24576 + cur * 8192;
    s16x8 af[4], bfr[4];
    const int c = lane >> 4;
#pragma unroll
    for (int i = 0; i < 4; ++i) {
      const int rA = wr * 64 + i * 16 + (lane & 15);
      af[i] = *(const s16x8*)(pA + rA * 64 + ((c ^ ((rA >> 1) & 3)) << 4));
      const int rB = wc * 64 + i * 16 + (lane & 15);
      bfr[i] = *(const s16x8*)(pB + rB * 64 + ((c ^ ((rB >> 1) & 3)) << 4));
    }
    __builtin_amdgcn_s_setprio(1);
#pragma unroll
    for (int i = 0; i < 4; ++i)
#pragma unroll
      for (int j = 0; j < 4; ++j)
        acc[i][j] = __builtin_amdgcn_mfma_f32_16x16x32_bf16(asbf(af[i]), asbf(bfr[j]),
                                                            acc[i][j], 0, 0, 0);
    __builtin_amdgcn_s_setprio(0);
    cur = (cur == 2) ? 0 : cur + 1;
    stg = (stg == 2) ? 0 : stg + 1;
  }

  if (MODE == 0) {
    if (o0 < 1024) {
      // Q/K: route through LDS for fully-coalesced 16B stores (256B/row)
      __syncthreads();  // all compute reads done; smem reusable
      const float sc = (o0 < 512) ? kQS : 1.0f;
      unsigned short* tile = (unsigned short*)smem;  // [128][136] u16 (34.8KB)
#pragma unroll
      for (int j = 0; j < 4; ++j) {
        const int o = wc * 64 + j * 16 + (lane & 15);
        const float bs = bias[o0 + o];
#pragma unroll
        for (int i = 0; i < 4; ++i)
#pragma unroll
          for (int r = 0; r < 4; ++r) {
            const int n = wr * 64 + i * 16 + ((lane >> 4) << 2) + r;
            tile[n * 136 + o] = f2bf((acc[i][j][r] + bs) * sc);
          }
      }
      __syncthreads();
#pragma unroll
      for (int it = 0; it < 8; ++it) {
        const int n = it * 16 + (t >> 4);
        const int c8 = t & 15;
        *(uint4*)(qkT + (rowb + n0 + n) * (size_t)kO + o0 + c8 * 8) =
            *(const uint4*)(tile + n * 136 + c8 * 8);
      }
    } else {
      // V: d-major packed, already 8B-vector stores
#pragma unroll
      for (int j = 0; j < 4; ++j) {
        const int o = o0 + wc * 64 + j * 16 + (lane & 15);
        const float bs = bias[o];
#pragma unroll
        for (int i = 0; i < 4; ++i) {
          const int nb = n0 + wr * 64 + ((lane >> 4) << 2) + i * 16;
          unsigned short pk[4];
#pragma unroll
          for (int r = 0; r < 4; ++r) pk[r] = f2bf(acc[i][j][r] + bs);
          *(uint2*)(vbuf + ((size_t)b * 512 + (o - 1024)) * kN + nb) = *(uint2*)pk;
        }
      }
    }
  } else {
    const int baseN = n0 + wr * 64 + ((lane >> 4) << 2);
#pragma unroll
    for (int j = 0; j < 4; ++j) {
      const int o = o0 + wc * 64 + j * 16 + (lane & 15);
      const float bs = bias[o];
#pragma unroll
      for (int i = 0; i < 4; ++i) {
        const int nb = baseN + i * 16;
        const size_t oo = ((size_t)b * kC + o) * kN + nb;
        const f32x4 xv = *(const f32x4*)(xres + oo);
        f32x4 ov;
        ov[0] = acc[i][j][0] + bs + xv[0];
        ov[1] = acc[i][j][1] + bs + xv[1];
        ov[2] = acc[i][j][2] + bs + xv[2];
        ov[3] = acc[i][j][3] + bs + xv[3];
        *(f32x4*)(outp + oo) = ov;
      }
    }
  }
}

// ---------------- flash attention v9 (proven 52.0us): split-half S + single-buf V ------
// Per tile: [vmcnt(0); barrier] -> stageV -> stageK(next)
//   -> QK^T half0 (K rows 0-31, one f32x16) -> exp2 in place -> pack ks{0,1}
//   -> [vmcnt(4): V landed, K prefetch rides; barrier] -> PV ks{0,1}
//   -> QK^T half1 (K rows 32-63, SAME regs) -> exp2 -> pack ks{2,3} -> PV ks{2,3}
// The qk1/pv0 interleave across co-resident waves (phase diversity) is load-bearing:
// v13's "both QK halves first" variant regressed 52->59us by removing it.
__global__ __launch_bounds__(256, 3) void k_attn(const unsigned short* __restrict__ qkT,
                                                 const unsigned short* __restrict__ vbuf,
                                                 unsigned short* __restrict__ aoT) {
  const int bh = blockIdx.x, qt = blockIdx.y;
  const int b = bh >> 2, h = bh & 3;
  const int t = threadIdx.x, lane = t & 63, wid = t >> 6;
  const int l31 = lane & 31, hi = lane >> 5;
  __shared__ unsigned short sK[2][64 * 128];  // [m][d] swizzled, double-buffered (32KB)
  __shared__ unsigned short sV[128 * 64];     // [d][m] swizzled, single (16KB)
  __shared__ float sL[4][32];
  const int qrow0 = qt * 128 + wid * 32;
  // Q as B-operand frags: row n = qrow0+l31, k(d) = kk*16 + hi*8 + {0..7}
  s16x8 qf[8];
#pragma unroll
  for (int kk = 0; kk < 8; ++kk)
    qf[kk] = *(const s16x8*)(qkT + ((size_t)b * kN + qrow0 + l31) * kO + h * 128 +
                             kk * 16 + hi * 8);
  f32x16 oc[4];
#pragma unroll
  for (int df = 0; df < 4; ++df)
#pragma unroll
    for (int r = 0; r < 16; ++r) oc[df][r] = 0.f;
  float lpart = 0.f;

  auto stageK = [&](int buf, int m0) {  // 4 vmcnt events
#pragma unroll
    for (int p = 0; p < 4; ++p) {
      const int id = p * 256 + t;
      const int row = id >> 4, cp = id & 15, cl = cp ^ (row & 7);
      gl_lds16(qkT + ((size_t)b * kN + m0 + row) * kO + 512 + h * 128 + cl * 8,
               (char*)sK[buf] + (p * 256 + wid * 64) * 16);
    }
  };
  auto stageV = [&](int m0) {  // 4 vmcnt events
#pragma unroll
    for (int p = 0; p < 4; ++p) {
      const int id = p * 256 + t;
      const int row = id >> 3, cp = id & 7, cl = cp ^ (row & 7);
      gl_lds16(vbuf + ((size_t)b * 512 + h * 128 + row) * kN + m0 + cl * 8,
               (char*)sV + (p * 256 + wid * 64) * 16);
    }
  };
  // one S-half: QK^T over 32 K-rows -> exp2 -> pack 2 ks-frags; PV'd by caller
  auto qkhalf = [&](int cur, int rbase, float& ps, uint32_t paw[2][4]) {
    float p[16];
    {
      f32x16 sa;
#pragma unroll
      for (int r = 0; r < 16; ++r) sa[r] = 0.f;
      __builtin_amdgcn_s_setprio(1);
#pragma unroll
      for (int kk = 0; kk < 8; ++kk) {
        const int c0 = kk * 2 + hi;
        const int r0 = rbase + l31;
        s16x8 kf = *(const s16x8*)((const char*)sK[cur] + r0 * 256 + ((c0 ^ (r0 & 7)) << 4));
        sa = __builtin_amdgcn_mfma_f32_32x32x16_bf16(asbf(kf), asbf(qf[kk]), sa, 0, 0, 0);
      }
      __builtin_amdgcn_s_setprio(0);
#pragma unroll
      for (int r = 0; r < 16; ++r) { p[r] = EXP2(sa[r]); ps += p[r]; }
    }
#pragma unroll
    for (int half = 0; half < 2; ++half) {
      const int base = half * 8;
      uint32_t a0 = cvtpk(p[base + 0], p[base + 1]);
      uint32_t b0 = cvtpk(p[base + 4], p[base + 5]);
      asm volatile("v_permlane32_swap_b32 %0, %1" : "+v"(a0), "+v"(b0));
      uint32_t a1 = cvtpk(p[base + 2], p[base + 3]);
      uint32_t b1 = cvtpk(p[base + 6], p[base + 7]);
      asm volatile("v_permlane32_swap_b32 %0, %1" : "+v"(a1), "+v"(b1));
      paw[half][0] = a0; paw[half][1] = a1; paw[half][2] = b0; paw[half][3] = b1;
    }
  };
  auto pv2 = [&](int ksbase, const uint32_t paw[2][4]) {  // PV for ks=ksbase,ksbase+1
    __builtin_amdgcn_s_setprio(1);
#pragma unroll
    for (int k2 = 0; k2 < 2; ++k2) {
      union { uint32_t w[4]; s16x8 v; } pa;
      pa.w[0] = paw[k2][0]; pa.w[1] = paw[k2][1]; pa.w[2] = paw[k2][2]; pa.w[3] = paw[k2][3];
      const int cv = (ksbase + k2) * 2 + hi;
#pragma unroll
      for (int df = 0; df < 4; ++df) {
        const int rv = df * 32 + l31;
        s16x8 vf = *(const s16x8*)((const char*)sV + rv * 128 + ((cv ^ (rv & 7)) << 4));
        oc[df] = __builtin_amdgcn_mfma_f32_32x32x16_bf16(asbf(pa.v), asbf(vf), oc[df], 0, 0, 0);
      }
    }
    __builtin_amdgcn_s_setprio(0);
  };

  stageK(0, 0);
#pragma unroll 1
  for (int mt = 0; mt < 16; ++mt) {
    const int cur = mt & 1;
    // top: K(mt) landed (only K outstanding); all waves done with sV + sK[cur^1]
    asm volatile("s_waitcnt vmcnt(0)" ::: "memory");
    __builtin_amdgcn_s_barrier();
    stageV(mt * 64);                              // V first: drained by vmcnt(4) mid-tile
    if (mt < 15) stageK(cur ^ 1, (mt + 1) * 64);  // K prefetch rides across whole tile
    float ps = 0.f;
    uint32_t paw[2][4];
    // ---- half 0: K rows 0-31 -> S^T, softmax, pack ks{0,1} ----
    qkhalf(cur, 0, ps, paw);
    // mid: V(mt) landed (vmcnt(4): K(mt+1)'s 4 loads still fly); barrier => all waves' V in
    if (mt < 15) {
      asm volatile("s_waitcnt vmcnt(4)" ::: "memory");
    } else {
      asm volatile("s_waitcnt vmcnt(0)" ::: "memory");
    }
    __builtin_amdgcn_s_barrier();
    pv2(0, paw);
    // ---- half 1: K rows 32-63, same registers -> pack ks{2,3}, PV ----
    qkhalf(cur, 32, ps, paw);
    pv2(2, paw);
    lpart += ps;
  }
  // ---- finalize: row sums, normalize, store ----
  lpart += __shfl_xor(lpart, 32);  // combine hi/lo m-halves -> full row sum for n=l31
  if (hi == 0) sL[wid][l31] = lpart;
  float inv[16];
#pragma unroll
  for (int r = 0; r < 16; ++r) {
    const int crow = (r & 3) + 8 * (r >> 2) + 4 * hi;
    inv[r] = 1.f / sL[wid][crow];
  }
#pragma unroll
  for (int df = 0; df < 4; ++df) {
    const int d = df * 32 + l31;
#pragma unroll
    for (int r = 0; r < 16; ++r) {
      const int n = qrow0 + (r & 3) + 8 * (r >> 2) + 4 * hi;
      aoT[((size_t)b * kN + n) * kC + h * 128 + d] = bfbits(oc[df][r] * inv[r]);
    }
  }
}

extern "C" void kernel_launch(void* const* d_in, const int* in_sizes, int n_in,
                              void* d_out, int out_size, void* d_ws, size_t ws_size,
                              hipStream_t stream) {
  const float* x = (const float*)d_in[0];
  const float* norm_w = (const float*)d_in[1];
  const float* norm_b = (const float*)d_in[2];
  const float* qkv_w = (const float*)d_in[3];
  const float* qkv_b = (const float*)d_in[4];
  const float* proj_w = (const float*)d_in[5];
  const float* proj_b = (const float*)d_in[6];
  float* out = (float*)d_out;
  char* ws = (char*)d_ws;
  const size_t OFF_MEAN = 0;
  const size_t OFF_RSTD = 2048;
  const size_t OFF_WQ = 4096;
  const size_t OFF_WP = OFF_WQ + (size_t)1536 * 512 * 2;
  const size_t OFF_XT = OFF_WP + (size_t)512 * 512 * 2;
  const size_t OFF_QKT = OFF_XT + (size_t)16 * 1024 * 512 * 2;
  const size_t OFF_V = OFF_QKT + (size_t)16 * 1024 * 1536 * 2;
  const size_t NEED = OFF_V + (size_t)16 * 512 * 1024 * 2;  // ~86 MB
  if (ws_size < NEED) return;
  unsigned short* wq = (unsigned short*)(ws + OFF_WQ);
  unsigned short* wp = (unsigned short*)(ws + OFF_WP);
  unsigned short* xt = (unsigned short*)(ws + OFF_XT);
  unsigned short* qkT = (unsigned short*)(ws + OFF_QKT);
  unsigned short* vb = (unsigned short*)(ws + OFF_V);
  unsigned short* aoT = xt;  // xhat is dead after qkv GEMM; reuse for attn output

  k_gnw<<<1536, 256, 0, stream>>>(x, norm_w, norm_b, xt, qkv_w, proj_w, wq, wp);
  k_gemm<0><<<dim3(96, 16), 256, 0, stream>>>(xt, wq, qkv_b, qkT, vb, nullptr, nullptr);
  k_attn<<<dim3(64, 8), 256, 0, stream>>>(qkT, vb, aoT);
  k_gemm<1><<<dim3(32, 16), 256, 0, stream>>>(aoT, wp, proj_b, nullptr, nullptr, x, out);
}